// Round 4
// baseline (198.807 us; speedup 1.0000x reference)
//
#include <hip/hip_runtime.h>

// GAE reverse scan: adv[t] = delta[t] + (gamma*lambda)*adv[t+1]
// delta[t] = reward[t] + gamma*value[t+1] - value[t]
//
// 2-pass sum-first + recompute structure (R1/R2), R4: chunk L 16 -> 8.
// R3 post-mortem: grid (16,64)=1024 blocks = 4096 waves caps occupancy at 50%
// (measured 28%), VGPR=36 shows compiler sank the load batch -> ~2.9 TB/s
// effective, latency-bound. L=8 doubles the grid (2048 blocks = 8192 waves =
// 100% occupancy cap) to double loads-in-flight chip-wide.
//   K1 gae_sum : per-(chunk, col4) weighted chunk sum S_c (reads 131 MB, writes 8 MB)
//   K2 gae_out : fold carry from S (L2/L3-hot suffix walk), recompute local
//                scan seeded with carry, write out ONCE (nontemporal).
// S is (C, B) = 8 MiB at L=8; guarded by ws_size with L=16 fallback.

constexpr int T_ = 1024;
constexpr int B_ = 16384;
constexpr float GAMMA = 0.99f;
constexpr float COEF  = (float)(0.99 * 0.97);

__host__ __device__ constexpr float pow_coef(int n) {
    float p = 1.0f;
    for (int i = 0; i < n; ++i) p *= COEF;
    return p;
}

typedef float f32x4 __attribute__((ext_vector_type(4)));

static __device__ __forceinline__ void store_nt(float* p, float4 v) {
    f32x4 nv = {v.x, v.y, v.z, v.w};
    __builtin_nontemporal_store(nv, (f32x4*)p);
}

// ---------------- K1: weighted chunk sums only ----------------
template<int L>
__global__ __launch_bounds__(256) void gae_sum(
    const float* __restrict__ value,   // (T+1, B)
    const float* __restrict__ reward,  // (T, B)
    float* __restrict__ S)             // (C, B)
{
    const int c4    = blockIdx.x * 256 + threadIdx.x;
    const int chunk = blockIdx.y;
    const size_t b  = (size_t)c4 * 4;
    const int t0    = chunk * L;

    // Batch loads: L+1 value rows + L reward rows in flight.
    float4 v[L + 1];
    float4 r[L];
    #pragma unroll
    for (int i = 0; i <= L; ++i)
        v[i] = *(const float4*)(value + (size_t)(t0 + i) * B_ + b);
    #pragma unroll
    for (int i = 0; i < L; ++i)
        r[i] = *(const float4*)(reward + (size_t)(t0 + i) * B_ + b);

    float4 s = make_float4(0.f, 0.f, 0.f, 0.f);
    #pragma unroll
    for (int i = L - 1; i >= 0; --i) {
        s.x = (r[i].x + GAMMA * v[i + 1].x - v[i].x) + COEF * s.x;
        s.y = (r[i].y + GAMMA * v[i + 1].y - v[i].y) + COEF * s.y;
        s.z = (r[i].z + GAMMA * v[i + 1].z - v[i].z) + COEF * s.z;
        s.w = (r[i].w + GAMMA * v[i + 1].w - v[i].w) + COEF * s.w;
    }
    *(float4*)(S + (size_t)chunk * B_ + b) = s;
}

// ---------------- K2: inline carry + recompute local scan + write out -------
template<int L>
__global__ __launch_bounds__(256) void gae_out(
    const float* __restrict__ value,   // (T+1, B)  L3-hot from K1
    const float* __restrict__ reward,  // (T, B)    L3-hot from K1
    const float* __restrict__ S,       // (C, B)    L2-hot, reused C/2 x
    float* __restrict__ out)           // (T, B)    written once, nontemporal
{
    constexpr int C = T_ / L;
    constexpr float CL = pow_coef(L);  // COEF^L

    const int c4    = blockIdx.x * 256 + threadIdx.x;
    const int chunk = blockIdx.y;
    const size_t b  = (size_t)c4 * 4;
    const int t0    = chunk * L;

    // Issue the big input batch first so loads are in flight while the
    // carry chain (L2-hit latency) resolves.
    float4 v[L + 1];
    float4 r[L];
    #pragma unroll
    for (int i = 0; i <= L; ++i)
        v[i] = *(const float4*)(value + (size_t)(t0 + i) * B_ + b);
    #pragma unroll
    for (int i = 0; i < L; ++i)
        r[i] = *(const float4*)(reward + (size_t)(t0 + i) * B_ + b);

    // carry entering chunk = sum_{j>chunk} CL^(j-chunk-1) * S_j, rolled in
    // reverse. chunk is wave-uniform (blockIdx.y) -> scalar loop, no divergence.
    // Loads are address-independent (prefetchable); only the FMA chain is
    // dependent (~C * 8 cy, negligible).
    float4 a = make_float4(0.f, 0.f, 0.f, 0.f);
    for (int j = C - 1; j > chunk; --j) {
        float4 s = *(const float4*)(S + (size_t)j * B_ + b);
        a.x = s.x + CL * a.x;
        a.y = s.y + CL * a.y;
        a.z = s.z + CL * a.z;
        a.w = s.w + CL * a.w;
    }

    // Local scan seeded with the carry; write out exactly once.
    #pragma unroll
    for (int i = L - 1; i >= 0; --i) {
        a.x = (r[i].x + GAMMA * v[i + 1].x - v[i].x) + COEF * a.x;
        a.y = (r[i].y + GAMMA * v[i + 1].y - v[i].y) + COEF * a.y;
        a.z = (r[i].z + GAMMA * v[i + 1].z - v[i].z) + COEF * a.z;
        a.w = (r[i].w + GAMMA * v[i + 1].w - v[i].w) + COEF * a.w;
        store_nt(out + (size_t)(t0 + i) * B_ + b, a);
    }
}

extern "C" void kernel_launch(void* const* d_in, const int* in_sizes, int n_in,
                              void* d_out, int out_size, void* d_ws, size_t ws_size,
                              hipStream_t stream) {
    const float* value  = (const float*)d_in[0];   // (T+1, B)
    const float* reward = (const float*)d_in[1];   // (T, B)
    float* out = (float*)d_out;
    float* S   = (float*)d_ws;

    dim3 block(256);

    // Preferred: L=8 (2048 blocks, 100% occupancy cap). Needs 8 MiB workspace.
    if (ws_size >= (size_t)(T_ / 8) * B_ * sizeof(float)) {
        dim3 grid(B_ / 4 / 256, T_ / 8);        // (16, 128)
        gae_sum<8><<<grid, block, 0, stream>>>(value, reward, S);
        gae_out<8><<<grid, block, 0, stream>>>(value, reward, S, out);
    } else {
        dim3 grid(B_ / 4 / 256, T_ / 16);       // (16, 64)
        gae_sum<16><<<grid, block, 0, stream>>>(value, reward, S);
        gae_out<16><<<grid, block, 0, stream>>>(value, reward, S, out);
    }
}

// Round 5
// 189.716 us; speedup vs baseline: 1.0479x; 1.0479x over previous
//
#include <hip/hip_runtime.h>

// GAE reverse scan: adv[t] = delta[t] + (gamma*lambda)*adv[t+1]
// delta[t] = reward[t] + gamma*value[t+1] - value[t]
//
// R5: 3-pass, L=8, with ASM LIVENESS PINS.
// R4 post-mortem: VGPR=36 proved the compiler sank the "batched" loads back
// into the scan (~3 loads/wave outstanding -> ~3 TB/s effective, latency-
// bound). asm volatile("" :: "v"(x)) pins force every loaded value to
// materialize BEFORE the scan -> 17 float4 in flight per wave.
// Also: R4's in-gae_out carry walk (avg 64 S-rows/block, ~512 MB L2 logical)
// was 4x the main-stream load count. Reinstated tiny gae_carry pass (in-place,
// register-batched, pinned) so gae_out loads exactly ONE carry row.
//   K1 gae_sum  : S_c = sum_k COEF^k * delta[8c+k]      (reads 131 MB, writes 8 MB)
//   K2 gae_carry: S[c] <- sum_{j>c} CL^(j-c-1) S[j]     (in place, 64 blocks)
//   K3 gae_out  : recompute local scan seeded with carry, write out ONCE (nt).

constexpr int T_ = 1024;
constexpr int B_ = 16384;
constexpr float GAMMA = 0.99f;
constexpr float COEF  = (float)(0.99 * 0.97);

__host__ __device__ constexpr float pow_coef(int n) {
    float p = 1.0f;
    for (int i = 0; i < n; ++i) p *= COEF;
    return p;
}

typedef float f32x4 __attribute__((ext_vector_type(4)));

static __device__ __forceinline__ void store_nt(float* p, float4 v) {
    f32x4 nv = {v.x, v.y, v.z, v.w};
    __builtin_nontemporal_store(nv, (f32x4*)p);
}

// Force a float4's lanes live in VGPRs at this program point (defeats load
// sinking; rule #17). No code emitted.
static __device__ __forceinline__ void pin(const float4& f) {
    asm volatile("" :: "v"(f.x), "v"(f.y), "v"(f.z), "v"(f.w));
}

// ---------------- K1: weighted chunk sums only ----------------
template<int L>
__global__ __launch_bounds__(256) void gae_sum(
    const float* __restrict__ value,   // (T+1, B)
    const float* __restrict__ reward,  // (T, B)
    float* __restrict__ S)             // (C, B)
{
    const int c4    = blockIdx.x * 256 + threadIdx.x;
    const int chunk = blockIdx.y;
    const size_t b  = (size_t)c4 * 4;
    const int t0    = chunk * L;

    float4 v[L + 1];
    float4 r[L];
    #pragma unroll
    for (int i = 0; i <= L; ++i)
        v[i] = *(const float4*)(value + (size_t)(t0 + i) * B_ + b);
    #pragma unroll
    for (int i = 0; i < L; ++i)
        r[i] = *(const float4*)(reward + (size_t)(t0 + i) * B_ + b);
    // Pin the whole batch: all 2L+1 loads issued before the scan consumes any.
    #pragma unroll
    for (int i = 0; i <= L; ++i) pin(v[i]);
    #pragma unroll
    for (int i = 0; i < L; ++i) pin(r[i]);

    float4 s = make_float4(0.f, 0.f, 0.f, 0.f);
    #pragma unroll
    for (int i = L - 1; i >= 0; --i) {
        s.x = (r[i].x + GAMMA * v[i + 1].x - v[i].x) + COEF * s.x;
        s.y = (r[i].y + GAMMA * v[i + 1].y - v[i].y) + COEF * s.y;
        s.z = (r[i].z + GAMMA * v[i + 1].z - v[i].z) + COEF * s.z;
        s.w = (r[i].w + GAMMA * v[i + 1].w - v[i].w) + COEF * s.w;
    }
    *(float4*)(S + (size_t)chunk * B_ + b) = s;
}

// ---------------- K2: in-place carry scan, one thread per scalar column ----
template<int C>
__global__ __launch_bounds__(256) void gae_carry(float* __restrict__ S)
{
    constexpr float CL = pow_coef(T_ / C);   // COEF^L
    const int col = blockIdx.x * 256 + threadIdx.x;   // 0..B-1

    float s[C];
    #pragma unroll
    for (int j = 0; j < C; ++j)
        s[j] = S[(size_t)j * B_ + col];
    #pragma unroll
    for (int j = 0; j < C; ++j)
        asm volatile("" :: "v"(s[j]));                // keep all C loads in flight

    float run = 0.f;
    #pragma unroll
    for (int j = C - 1; j >= 0; --j) {
        S[(size_t)j * B_ + col] = run;                // carry entering chunk j
        run = s[j] + CL * run;
    }
}

// ---------------- K3: recompute local scan seeded with carry --------------
template<int L>
__global__ __launch_bounds__(256) void gae_out(
    const float* __restrict__ value,   // (T+1, B)  L3-hot from K1
    const float* __restrict__ reward,  // (T, B)    L3-hot from K1
    const float* __restrict__ S,       // (C, B)    now holds carries
    float* __restrict__ out)           // (T, B)    written once, nontemporal
{
    const int c4    = blockIdx.x * 256 + threadIdx.x;
    const int chunk = blockIdx.y;
    const size_t b  = (size_t)c4 * 4;
    const int t0    = chunk * L;

    // carry first (heads the FMA chain), then the big batch; pin everything.
    float4 carry = *(const float4*)(S + (size_t)chunk * B_ + b);
    float4 v[L + 1];
    float4 r[L];
    #pragma unroll
    for (int i = 0; i <= L; ++i)
        v[i] = *(const float4*)(value + (size_t)(t0 + i) * B_ + b);
    #pragma unroll
    for (int i = 0; i < L; ++i)
        r[i] = *(const float4*)(reward + (size_t)(t0 + i) * B_ + b);
    pin(carry);
    #pragma unroll
    for (int i = 0; i <= L; ++i) pin(v[i]);
    #pragma unroll
    for (int i = 0; i < L; ++i) pin(r[i]);

    float4 a = carry;
    #pragma unroll
    for (int i = L - 1; i >= 0; --i) {
        a.x = (r[i].x + GAMMA * v[i + 1].x - v[i].x) + COEF * a.x;
        a.y = (r[i].y + GAMMA * v[i + 1].y - v[i].y) + COEF * a.y;
        a.z = (r[i].z + GAMMA * v[i + 1].z - v[i].z) + COEF * a.z;
        a.w = (r[i].w + GAMMA * v[i + 1].w - v[i].w) + COEF * a.w;
        store_nt(out + (size_t)(t0 + i) * B_ + b, a);
    }
}

extern "C" void kernel_launch(void* const* d_in, const int* in_sizes, int n_in,
                              void* d_out, int out_size, void* d_ws, size_t ws_size,
                              hipStream_t stream) {
    const float* value  = (const float*)d_in[0];   // (T+1, B)
    const float* reward = (const float*)d_in[1];   // (T, B)
    float* out = (float*)d_out;
    float* S   = (float*)d_ws;

    dim3 block(256);
    dim3 gridC(B_ / 256);                           // 64 blocks, scalar columns

    if (ws_size >= (size_t)(T_ / 8) * B_ * sizeof(float)) {
        // L=8: 2048 blocks for the streaming kernels (100% occupancy cap).
        dim3 grid(B_ / 4 / 256, T_ / 8);            // (16, 128)
        gae_sum<8>  <<<grid,  block, 0, stream>>>(value, reward, S);
        gae_carry<T_/8><<<gridC, block, 0, stream>>>(S);
        gae_out<8>  <<<grid,  block, 0, stream>>>(value, reward, S, out);
    } else {
        dim3 grid(B_ / 4 / 256, T_ / 16);           // (16, 64)
        gae_sum<16> <<<grid,  block, 0, stream>>>(value, reward, S);
        gae_carry<T_/16><<<gridC, block, 0, stream>>>(S);
        gae_out<16> <<<grid,  block, 0, stream>>>(value, reward, S, out);
    }
}